// Round 1
// baseline (279.772 us; speedup 1.0000x reference)
//
#include <hip/hip_runtime.h>

#define BB 2
#define TT 1024
#define DD 512
#define HH 8
#define FF 16
#define HDIM 64
#define BT (BB*TT)   // 2048

// ---------------------------------------------------------------------------
// Kernel 1: fused QKV projection.  C = X @ [Wq;Wk;Wv]^T  (2048 x 768, K=512)
// Tiled fp32 GEMM: 64x64 tile, BK=16, 256 threads, 4x4 per thread.
// Outputs written directly in (b,h,t,f) / (b,h,t,hd) layout.
// ---------------------------------------------------------------------------
__global__ __launch_bounds__(256) void qkv_gemm_kernel(
    const float* __restrict__ X, const float* __restrict__ Wq,
    const float* __restrict__ Wk, const float* __restrict__ Wv,
    float* __restrict__ Qo, float* __restrict__ Ko, float* __restrict__ Vo)
{
    __shared__ float As[16][64];
    __shared__ float Bs[16][64];
    const int m0 = blockIdx.x * 64;
    const int n0 = blockIdx.y * 64;
    const int tid = threadIdx.x;
    const int tx = tid & 15, ty = tid >> 4;
    const int lrow = tid >> 2, lseg = tid & 3;

    const float* Wb; int nb;
    if (n0 < 128)      { Wb = Wq; nb = n0; }
    else if (n0 < 256) { Wb = Wk; nb = n0 - 128; }
    else               { Wb = Wv; nb = n0 - 256; }

    float acc[4][4] = {};
    for (int k0 = 0; k0 < DD; k0 += 16) {
        float4 a  = *(const float4*)(X  + (size_t)(m0 + lrow) * DD + k0 + lseg * 4);
        float4 bv = *(const float4*)(Wb + (size_t)(nb + lrow) * DD + k0 + lseg * 4);
        __syncthreads();
        As[lseg*4+0][lrow] = a.x;  As[lseg*4+1][lrow] = a.y;
        As[lseg*4+2][lrow] = a.z;  As[lseg*4+3][lrow] = a.w;
        Bs[lseg*4+0][lrow] = bv.x; Bs[lseg*4+1][lrow] = bv.y;
        Bs[lseg*4+2][lrow] = bv.z; Bs[lseg*4+3][lrow] = bv.w;
        __syncthreads();
        #pragma unroll
        for (int k = 0; k < 16; ++k) {
            float4 av = *(const float4*)&As[k][ty*4];
            float4 bw = *(const float4*)&Bs[k][tx*4];
            const float* ap = (const float*)&av;
            const float* bp = (const float*)&bw;
            #pragma unroll
            for (int i = 0; i < 4; ++i)
                #pragma unroll
                for (int j = 0; j < 4; ++j)
                    acc[i][j] = fmaf(ap[i], bp[j], acc[i][j]);
        }
    }

    #pragma unroll
    for (int i = 0; i < 4; ++i) {
        const int rg = m0 + ty*4 + i;
        const int bb = rg >> 10, t = rg & 1023;
        #pragma unroll
        for (int j = 0; j < 4; ++j) {
            const int cg = n0 + tx*4 + j;
            const float val = acc[i][j];
            if (cg < 128) {
                const int hh = cg >> 4, f = cg & 15;
                Qo[((size_t)(bb*HH + hh)*TT + t)*FF + f] = val;
            } else if (cg < 256) {
                const int c = cg - 128; const int hh = c >> 4, f = c & 15;
                Ko[((size_t)(bb*HH + hh)*TT + t)*FF + f] = val;
            } else {
                const int c = cg - 256; const int hh = c >> 6, dd = c & 63;
                Vo[((size_t)(bb*HH + hh)*TT + t)*HDIM + dd] = val;
            }
        }
    }
}

// ---------------------------------------------------------------------------
// Kernel 2: causal Taylor attention via closed-form scores.
// phi(q).phi(k) == 1 + s + s^2/2,  s = (q.k)/4.
// Block = one (b,h, 128-row q-tile). 256 threads: ty(0..31) owns 4 q-rows,
// tx(0..7) owns 8 v-columns. K/V chunks (128 rows) staged in LDS.
// ---------------------------------------------------------------------------
__global__ __launch_bounds__(256) void attn_kernel(
    const float* __restrict__ Q, const float* __restrict__ K,
    const float* __restrict__ V, float* __restrict__ Y)
{
    const int qt = blockIdx.x;   // 0..7
    const int bh = blockIdx.y;   // 0..15
    const int b = bh >> 3, h = bh & 7;
    const int tid = threadIdx.x;
    const int tx = tid & 7;
    const int ty = tid >> 3;     // 0..31

    __shared__ float Ks[128][16];
    __shared__ float Vs[128][64];

    // load this thread's 4 q-rows into registers
    float q[4][16];
    const float* Qb = Q + ((size_t)bh * TT + qt * 128) * FF;
    #pragma unroll
    for (int i = 0; i < 4; ++i) {
        #pragma unroll
        for (int s = 0; s < 4; ++s) {
            float4 t4 = *(const float4*)(Qb + (ty*4 + i)*FF + s*4);
            q[i][s*4+0] = t4.x; q[i][s*4+1] = t4.y;
            q[i][s*4+2] = t4.z; q[i][s*4+3] = t4.w;
        }
    }

    float num[4][8] = {};
    float den[4] = {};

    for (int kc = 0; kc <= qt; ++kc) {
        __syncthreads();
        const float4* Kb4 = (const float4*)(K + ((size_t)bh*TT + kc*128) * FF);
        float4* Ks4 = (float4*)&Ks[0][0];
        for (int u = tid; u < 512; u += 256) Ks4[u] = Kb4[u];
        const float4* Vb4 = (const float4*)(V + ((size_t)bh*TT + kc*128) * HDIM);
        float4* Vs4 = (float4*)&Vs[0][0];
        for (int u = tid; u < 2048; u += 256) Vs4[u] = Vb4[u];
        __syncthreads();

        const bool diag = (kc == qt);
        for (int kk = 0; kk < 128; ++kk) {
            float kv[16];
            #pragma unroll
            for (int s = 0; s < 4; ++s) {
                float4 t4 = *(const float4*)&Ks[kk][s*4];
                kv[s*4+0]=t4.x; kv[s*4+1]=t4.y; kv[s*4+2]=t4.z; kv[s*4+3]=t4.w;
            }
            float4 v0 = *(const float4*)&Vs[kk][tx*8];
            float4 v1 = *(const float4*)&Vs[kk][tx*8+4];
            #pragma unroll
            for (int i = 0; i < 4; ++i) {
                float s_ = 0.f;
                #pragma unroll
                for (int m = 0; m < 16; ++m) s_ = fmaf(q[i][m], kv[m], s_);
                s_ *= 0.25f;
                float p = fmaf(s_, fmaf(s_, 0.5f, 1.0f), 1.0f);  // 1 + s + s^2/2
                if (diag && kk > ty*4 + i) p = 0.f;              // causal mask
                den[i] += p;
                num[i][0] = fmaf(p, v0.x, num[i][0]);
                num[i][1] = fmaf(p, v0.y, num[i][1]);
                num[i][2] = fmaf(p, v0.z, num[i][2]);
                num[i][3] = fmaf(p, v0.w, num[i][3]);
                num[i][4] = fmaf(p, v1.x, num[i][4]);
                num[i][5] = fmaf(p, v1.y, num[i][5]);
                num[i][6] = fmaf(p, v1.z, num[i][6]);
                num[i][7] = fmaf(p, v1.w, num[i][7]);
            }
        }
    }

    #pragma unroll
    for (int i = 0; i < 4; ++i) {
        const int t = qt*128 + ty*4 + i;
        const float inv = 1.0f / (den[i] + 1e-12f);
        float4 o0, o1;
        o0.x = num[i][0]*inv; o0.y = num[i][1]*inv;
        o0.z = num[i][2]*inv; o0.w = num[i][3]*inv;
        o1.x = num[i][4]*inv; o1.y = num[i][5]*inv;
        o1.z = num[i][6]*inv; o1.w = num[i][7]*inv;
        float* Yp = Y + ((size_t)(b*TT + t))*DD + h*HDIM + tx*8;
        *(float4*)Yp = o0;
        *(float4*)(Yp+4) = o1;
    }
}

// ---------------------------------------------------------------------------
// Kernel 3: output projection.  Out = Y @ Wo^T  (2048 x 512, K=512)
// ---------------------------------------------------------------------------
__global__ __launch_bounds__(256) void out_gemm_kernel(
    const float* __restrict__ Yin, const float* __restrict__ Wo,
    float* __restrict__ Out)
{
    __shared__ float As[16][64];
    __shared__ float Bs[16][64];
    const int m0 = blockIdx.x * 64;
    const int n0 = blockIdx.y * 64;
    const int tid = threadIdx.x;
    const int tx = tid & 15, ty = tid >> 4;
    const int lrow = tid >> 2, lseg = tid & 3;

    float acc[4][4] = {};
    for (int k0 = 0; k0 < DD; k0 += 16) {
        float4 a  = *(const float4*)(Yin + (size_t)(m0 + lrow) * DD + k0 + lseg * 4);
        float4 bv = *(const float4*)(Wo  + (size_t)(n0 + lrow) * DD + k0 + lseg * 4);
        __syncthreads();
        As[lseg*4+0][lrow] = a.x;  As[lseg*4+1][lrow] = a.y;
        As[lseg*4+2][lrow] = a.z;  As[lseg*4+3][lrow] = a.w;
        Bs[lseg*4+0][lrow] = bv.x; Bs[lseg*4+1][lrow] = bv.y;
        Bs[lseg*4+2][lrow] = bv.z; Bs[lseg*4+3][lrow] = bv.w;
        __syncthreads();
        #pragma unroll
        for (int k = 0; k < 16; ++k) {
            float4 av = *(const float4*)&As[k][ty*4];
            float4 bw = *(const float4*)&Bs[k][tx*4];
            const float* ap = (const float*)&av;
            const float* bp = (const float*)&bw;
            #pragma unroll
            for (int i = 0; i < 4; ++i)
                #pragma unroll
                for (int j = 0; j < 4; ++j)
                    acc[i][j] = fmaf(ap[i], bp[j], acc[i][j]);
        }
    }

    #pragma unroll
    for (int i = 0; i < 4; ++i) {
        const int rg = m0 + ty*4 + i;
        #pragma unroll
        for (int j = 0; j < 4; ++j) {
            const int cg = n0 + tx*4 + j;
            Out[(size_t)rg * DD + cg] = acc[i][j];
        }
    }
}

// ---------------------------------------------------------------------------
extern "C" void kernel_launch(void* const* d_in, const int* in_sizes, int n_in,
                              void* d_out, int out_size, void* d_ws, size_t ws_size,
                              hipStream_t stream) {
    const float* X  = (const float*)d_in[0];   // (2,1024,512)
    const float* Wq = (const float*)d_in[1];   // (128,512)
    const float* Wk = (const float*)d_in[2];   // (128,512)
    const float* Wv = (const float*)d_in[3];   // (512,512)
    const float* Wo = (const float*)d_in[4];   // (512,512)
    float* out = (float*)d_out;                // (2,1024,512)

    float* ws = (float*)d_ws;
    float* Qw = ws;                        // 2*8*1024*16  = 262144
    float* Kw = Qw + (size_t)BB*HH*TT*FF;  // 262144
    float* Vw = Kw + (size_t)BB*HH*TT*FF;  // 2*8*1024*64 = 1048576
    float* Yw = Vw + (size_t)BB*HH*TT*HDIM;// 2048*512    = 1048576

    dim3 g1(BT/64, 768/64);   // 32 x 12
    qkv_gemm_kernel<<<g1, 256, 0, stream>>>(X, Wq, Wk, Wv, Qw, Kw, Vw);

    dim3 g2(TT/128, BB*HH);   // 8 x 16
    attn_kernel<<<g2, 256, 0, stream>>>(Qw, Kw, Vw, Yw);

    dim3 g3(BT/64, DD/64);    // 32 x 8
    out_gemm_kernel<<<g3, 256, 0, stream>>>(Yw, Wo, out);
}